// Round 11
// baseline (4734.594 us; speedup 1.0000x reference)
//
#include <hip/hip_runtime.h>
#include <cstdint>

// LSTM B=4096, T=512, D=H=25, 3 layers + MLP head + softmax.
// R11: single-wave MFMA, all-register weights, zero barriers.
//   One wave = 16 batches (MFMA N=16), 256 blocks x 64 thr = 1 wave/CU.
//   W frags (f16 hi + 4096*lo, interleaved-M so lane owns i,f,g,o of one
//   unit) in REGISTERS: 7 mt x 2 kt x 2 x f16x8 = 112 VGPR (R9 streamed
//   these from LDS = 28 b128/step + serialization -> its 4700cyc/step).
//   Per step: 4 ds_read_b128 (XH[16][72] f16, ~2-way) + 42 MFMA (7
//   independent mtile chains) + lane-local gate update + 14 ds_write_b16
//   publish + staged x/h with 2-step-deep global prefetch (regs, static
//   unroll only -> no scratch). No barriers anywhere; layer boundary =
//   s_waitcnt vmcnt(0) (same-wave ws store->load).
//   Numerics = R9 (verified absmax 4.9e-4): D1=Whi*Xhi,
//   D2=Whi*(4096 Xlo)+(4096 Wlo)*Xhi, dd=D1+D2/4096.

typedef _Float16 f16;
typedef f16  f16x8 __attribute__((ext_vector_type(8)));
typedef float f32x4 __attribute__((ext_vector_type(4)));

#define NT 512
#define ND 25
#define NB 16
#define LOSCALE 4096.0f
#define INVLO   2.44140625e-4f

__device__ __forceinline__ float exp2f_(float x){ return __builtin_amdgcn_exp2f(x); }
__device__ __forceinline__ float rcpf_(float x){ return __builtin_amdgcn_rcpf(x); }
__device__ __forceinline__ float sigf(float x){ return rcpf_(1.f + exp2f_(-1.442695041f*x)); }
__device__ __forceinline__ float tanhf_(float x){ return fmaf(2.f, rcpf_(1.f + exp2f_(-2.885390082f*x)), -1.f); }
__device__ __forceinline__ unsigned short f16b(f16 h){ union{f16 h; unsigned short s;} u; u.h=h; return u.s; }
__device__ __forceinline__ f16 b2f16(unsigned short s){ union{f16 h; unsigned short s;} u; u.s=s; return u.h; }

#define MFMA(a,b,c) __builtin_amdgcn_mfma_f32_16x16x32_f16((a),(b),(c),0,0,0)

template<bool ISL0>
__device__ __forceinline__ void layer_body(
    const int l, const int bb, const int bq, const int lg, const int lane,
    const float* __restrict__ xin, uint32_t* __restrict__ ws,
    const float* __restrict__ Wih, const float* __restrict__ Whh,
    const float* __restrict__ bih, const float* __restrict__ bhh,
    f16* __restrict__ XH_H, f16* __restrict__ XH_L, float* __restrict__ hout)
{
    // ---- W fragments into registers (per-layer, 112 VGPR) ----
    f16x8 wh[7][2], wl[7][2];
#pragma unroll
    for (int mt = 0; mt < 7; ++mt) {
        const int rp = mt*16 + bq;                // interleaved row; lane's A m-index = bq
        const bool wv = rp < 100;
        const int ro = wv ? ((rp&3)*ND + (rp>>2)) : 0;   // torch-order row
        const float* wri = Wih + ((size_t)l*100 + ro)*ND;
        const float* wrh = Whh + ((size_t)l*100 + ro)*ND;
        const float bsum = wv ? (bih[l*100+ro] + bhh[l*100+ro]) : 0.f;
#pragma unroll
        for (int kt = 0; kt < 2; ++kt) {
            f16x8 vh, vl;
#pragma unroll
            for (int i = 0; i < 8; ++i) {
                const int k = kt*32 + lg*8 + i;
                float w = 0.f;
                if (wv) {
                    if (k < ND)        w = wri[k];
                    else if (k < 2*ND) w = wrh[k-ND];
                    else if (k == 63)  w = bsum;
                }
                const f16 hi = (f16)w;
                vh[i] = hi; vl[i] = (f16)((w - (float)hi)*LOSCALE);
            }
            wh[mt][kt] = vh; wl[mt][kt] = vl;
        }
    }

    // ---- staging map: j=0..6, idx=lane+64j -> (bj,uj); j==6 valid iff lane<16 ----
    const float*    sx[7];
    const uint32_t* sw[7];
    uint32_t loff[7];
#pragma unroll
    for (int j = 0; j < 7; ++j) {
        const int idx = lane + 64*j;
        const int bj = idx / ND, uj = idx % ND;   // j==6 invalid lanes get harmless values
        sx[j]   = xin + (size_t)(bb + bj)*NT*ND + uj;
        sw[j]   = ws  + (size_t)(bb + bj)*NT*ND + uj;
        loff[j] = bj*72 + uj;
    }

    // ---- init: h-region=0, x_0 staged, prefetch x_1,x_2 ----
    float    xf1[7], xf2[7];
    uint32_t xp1[7], xp2[7];
#pragma unroll
    for (int j = 0; j < 7; ++j) {
        xf1[j]=xf2[j]=0.f; xp1[j]=xp2[j]=0u;
        const bool jv = (j < 6) || (lane < 16);
        if (jv) {
            XH_H[loff[j] + ND] = (f16)0.f;
            XH_L[loff[j] + ND] = (f16)0.f;
            if constexpr (ISL0) {
                const float v = sx[j][0];
                const f16 hi = (f16)v;
                XH_H[loff[j]] = hi; XH_L[loff[j]] = (f16)((v-(float)hi)*LOSCALE);
                xf1[j] = sx[j][1*ND];
                xf2[j] = sx[j][2*ND];
            } else {
                const uint32_t p = sw[j][0];
                XH_H[loff[j]] = b2f16((unsigned short)(p & 0xffffu));
                XH_L[loff[j]] = b2f16((unsigned short)(p >> 16));
                xp1[j] = sw[j][1*ND];
                xp2[j] = sw[j][2*ND];
            }
        }
    }

    uint32_t* const wsb = ws + (size_t)(bb + bq)*NT*ND;   // this lane's ws row base

    float c_[7], h_[7];
#pragma unroll
    for (int mt = 0; mt < 7; ++mt) { c_[mt] = 0.f; h_[mt] = 0.f; }

    for (int t = 0; t < NT; ++t) {
        // ---- B-frags (reads see prior-step writes: same-wave DS order) ----
        const f16x8 bh0 = *(const f16x8*)&XH_H[bq*72 +      lg*8];
        const f16x8 bh1 = *(const f16x8*)&XH_H[bq*72 + 32 + lg*8];
        const f16x8 bl0 = *(const f16x8*)&XH_L[bq*72 +      lg*8];
        const f16x8 bl1 = *(const f16x8*)&XH_L[bq*72 + 32 + lg*8];

        // ---- 7 independent mtile chains: 6 MFMA + lane-local update each ----
#pragma unroll
        for (int mt = 0; mt < 7; ++mt) {
            f32x4 d1 = {0,0,0,0}, d2 = {0,0,0,0};
            d1 = MFMA(wh[mt][0], bh0, d1); d1 = MFMA(wh[mt][1], bh1, d1);
            d2 = MFMA(wh[mt][0], bl0, d2); d2 = MFMA(wl[mt][0], bh0, d2);
            d2 = MFMA(wh[mt][1], bl1, d2); d2 = MFMA(wl[mt][1], bh1, d2);
            const f32x4 dd = d1 + d2 * INVLO;
            const float gi = sigf(dd[0]);
            const float gf = sigf(dd[1]);
            const float gg = tanhf_(dd[2]);
            const float go = sigf(dd[3]);
            c_[mt] = fmaf(gf, c_[mt], gi*gg);
            h_[mt] = go * tanhf_(c_[mt]);
        }

        // ---- publish h_t (lane owns unit u = mt*4+lg of batch bq) ----
#pragma unroll
        for (int mt = 0; mt < 7; ++mt) {
            const int u = mt*4 + lg;
            if ((mt < 6) || (lg == 0)) {          // u < 25
                const f16 hi = (f16)h_[mt];
                const f16 lo = (f16)((h_[mt] - (float)hi)*LOSCALE);
                XH_H[bq*72 + ND + u] = hi;
                XH_L[bq*72 + ND + u] = lo;
                if (l < 2)
                    wsb[(size_t)t*ND + u] = (uint32_t)f16b(hi) | ((uint32_t)f16b(lo) << 16);
            }
        }

        // ---- stage x_{t+1} (from regs), shift, prefetch x_{t+3} ----
        if (t + 1 < NT) {
#pragma unroll
            for (int j = 0; j < 7; ++j) {
                const bool jv = (j < 6) || (lane < 16);
                if (jv) {
                    f16 hi, lo;
                    if constexpr (ISL0) {
                        const float v = xf1[j];
                        hi = (f16)v; lo = (f16)((v - (float)hi)*LOSCALE);
                        xf1[j] = xf2[j];
                        if (t + 3 < NT) xf2[j] = sx[j][(size_t)(t+3)*ND];
                    } else {
                        const uint32_t p = xp1[j];
                        hi = b2f16((unsigned short)(p & 0xffffu));
                        lo = b2f16((unsigned short)(p >> 16));
                        xp1[j] = xp2[j];
                        if (t + 3 < NT) xp2[j] = sw[j][(size_t)(t+3)*ND];
                    }
                    XH_H[loff[j]] = hi;
                    XH_L[loff[j]] = lo;
                }
            }
        }
    }

#pragma unroll
    for (int mt = 0; mt < 7; ++mt) hout[mt] = h_[mt];
}

__global__ __launch_bounds__(64, 1)
void lstm11(const float* __restrict__ xin, const float* __restrict__ Wih,
            const float* __restrict__ Whh, const float* __restrict__ bih,
            const float* __restrict__ bhh, const float* __restrict__ W1,
            const float* __restrict__ b1,  const float* __restrict__ W2,
            const float* __restrict__ b2,  float* __restrict__ out,
            uint32_t* __restrict__ ws)
{
    // XH row: [x(25) | h(25) | 0(13) | bias=1.0 @63 | pad 64..71], 72 f16 = 144B
    __shared__ __align__(16) f16 XH_H[NB*72];
    __shared__ __align__(16) f16 XH_L[NB*72];
    __shared__ __align__(16) float hfin[NB][28];

    const int lane = threadIdx.x;       // one wave
    const int bq = lane & 15;
    const int lg = lane >> 4;
    const int bb = blockIdx.x * NB;

    for (int i = lane; i < NB*72; i += 64) { XH_H[i] = (f16)0.f; XH_L[i] = (f16)0.f; }
    if (lane < NB) XH_H[lane*72 + 63] = (f16)1.f;    // bias column
    // single wave: its own DS ops are in-order; later reads see these writes.

    float hfinal[7];
    layer_body<true >(0, bb, bq, lg, lane, xin, ws, Wih, Whh, bih, bhh, XH_H, XH_L, hfinal);
    asm volatile("s_waitcnt vmcnt(0)" ::: "memory");
    layer_body<false>(1, bb, bq, lg, lane, xin, ws, Wih, Whh, bih, bhh, XH_H, XH_L, hfinal);
    asm volatile("s_waitcnt vmcnt(0)" ::: "memory");
    layer_body<false>(2, bb, bq, lg, lane, xin, ws, Wih, Whh, bih, bhh, XH_H, XH_L, hfinal);

    // ---- head: relu(h W1^T + b1) W2^T + b2, softmax(14) ----
#pragma unroll
    for (int mt = 0; mt < 7; ++mt) {
        const int u = mt*4 + lg;
        if ((mt < 6) || (lg == 0)) hfin[bq][u] = hfinal[mt];
    }
    if (lane < NB) {
        const int b = lane;
        float u1[16];
#pragma unroll
        for (int r = 0; r < 16; ++r) {
            float acc = b1[r];
#pragma unroll
            for (int d = 0; d < ND; ++d) acc = fmaf(W1[r*ND + d], hfin[b][d], acc);
            u1[r] = fmaxf(acc, 0.f);
        }
        float lgt[14]; float m = -1e30f;
#pragma unroll
        for (int r = 0; r < 14; ++r) {
            float acc = b2[r];
#pragma unroll
            for (int k2 = 0; k2 < 16; ++k2) acc = fmaf(W2[r*16 + k2], u1[k2], acc);
            lgt[r] = acc; m = fmaxf(m, acc);
        }
        float s = 0.f;
#pragma unroll
        for (int r = 0; r < 14; ++r) { lgt[r] = exp2f_(1.442695041f*(lgt[r]-m)); s += lgt[r]; }
        const float inv = rcpf_(s);
#pragma unroll
        for (int r = 0; r < 14; ++r) out[(size_t)(bb+b)*14 + r] = lgt[r]*inv;
    }
}

extern "C" void kernel_launch(void* const* d_in, const int* in_sizes, int n_in,
                              void* d_out, int out_size, void* d_ws, size_t ws_size,
                              hipStream_t stream)
{
    const float* x   = (const float*)d_in[0];
    const float* Wih = (const float*)d_in[1];
    const float* Whh = (const float*)d_in[2];
    const float* bih = (const float*)d_in[3];
    const float* bhh = (const float*)d_in[4];
    const float* W1  = (const float*)d_in[5];
    const float* b1  = (const float*)d_in[6];
    const float* W2  = (const float*)d_in[7];
    const float* b2  = (const float*)d_in[8];
    float*    outp = (float*)d_out;
    uint32_t* ws   = (uint32_t*)d_ws;   // 4096*512*25*4 B = 210 MB packed {hi,lo}

    dim3 grid(4096 / NB), block(64);    // 256 blocks, 1 wave each
    hipLaunchKernelGGL(lstm11, grid, block, 0, stream,
                       x, Wih, Whh, bih, bhh, W1, b1, W2, b2, outp, ws);
}

// Round 12
// 2065.462 us; speedup vs baseline: 2.2923x; 2.2923x over previous
//
#include <hip/hip_runtime.h>

// LSTM B=4096, T=512, D=H=25, 3 layers + MLP head + softmax.
// R12: K-split VALU design. One wave = ONE batch (4096 waves), zero barriers.
//   lane -> (u = lane&31: unit, kh = lane>>5: K-half). Lane owns all 4 gate
//   rows (i,f,g,o) of unit u, K-slice kh (kh=0: x-part via Wih, kh=1: h-part
//   via Whh) = 100 weight floats = 50 f32x2.
//   Per step: 7 ds_read_b128 (own 25-float K-window; 2 addr groups = free
//   2-way broadcast) + 52 v_pk_fma + 4 __shfl_xor(.,32) cross-half combine +
//   lane-local gates/cell (redundant in both halves) + 2 ds_write_b32
//   (kh=1 publishes h, kh=0 stages x_{t+1}) + 1 global store (ws, l<2) +
//   1 prefetch load (3-step slack). Same-wave DS is in-order -> no barrier.
//   DS/step ~13 ops (R4 had 33) at HALF R4's wave-steps.
//   Layers sequential via fp32 ws; one s_waitcnt vmcnt(0) per boundary.

typedef float f32x2 __attribute__((ext_vector_type(2)));
typedef float f32x4 __attribute__((ext_vector_type(4)));

#define NT 512
#define ND 25

__device__ __forceinline__ float exp2f_(float x){ return __builtin_amdgcn_exp2f(x); }
__device__ __forceinline__ float rcpf_(float x){ return __builtin_amdgcn_rcpf(x); }
__device__ __forceinline__ float sigf(float x){ return rcpf_(1.f + exp2f_(-1.442695041f*x)); }
__device__ __forceinline__ float tanhf_(float x){ return fmaf(2.f, rcpf_(1.f + exp2f_(-2.885390082f*x)), -1.f); }
__device__ __forceinline__ void pkfma(f32x2& a, f32x2 w, f32x2 v) {
    asm("v_pk_fma_f32 %0, %1, %2, %0" : "+v"(a) : "v"(w), "v"(v));
}
#define LO2(v) __builtin_shufflevector(v, v, 0, 1)
#define HI2(v) __builtin_shufflevector(v, v, 2, 3)

#define M12(F) F(0) F(1) F(2) F(3) F(4) F(5) F(6) F(7) F(8) F(9) F(10) F(11)

#define WDECL(m) f32x2 wI##m, wF##m, wG##m, wO##m;
#define WLOAD(m) wI##m = (f32x2){pI_[2*(m)], pI_[2*(m)+1]}; \
                 wF##m = (f32x2){pF_[2*(m)], pF_[2*(m)+1]}; \
                 wG##m = (f32x2){pG_[2*(m)], pG_[2*(m)+1]}; \
                 wO##m = (f32x2){pO_[2*(m)], pO_[2*(m)+1]};

#define DOTP(m, V) pkfma(aI, wI##m, (V)); pkfma(aF, wF##m, (V)); \
                   pkfma(aG, wG##m, (V)); pkfma(aO, wO##m, (V));

__global__ __launch_bounds__(64, 3)
void lstm12(const float* __restrict__ xin, const float* __restrict__ Wih,
            const float* __restrict__ Whh, const float* __restrict__ bih,
            const float* __restrict__ bhh, const float* __restrict__ W1,
            const float* __restrict__ b1,  const float* __restrict__ W2,
            const float* __restrict__ b2,  float* __restrict__ out,
            float* __restrict__ ws)
{
    // v[parity][0..24]=x, [25..31]=0, [32..56]=h, [57..63]=0
    __shared__ __align__(16) float v[2][64];

    const int lane = threadIdx.x;        // one wave per block
    const int u    = lane & 31;
    const int kh   = lane >> 5;
    const int uc   = (u < ND) ? u : ND - 1;
    const bool au  = (u < ND);
    const int b    = blockIdx.x;

    v[0][lane] = 0.f; v[1][lane] = 0.f;  // zero everything (incl. pads)

    WDECL(0) WDECL(1) WDECL(2) WDECL(3) WDECL(4) WDECL(5) WDECL(6)
    WDECL(7) WDECL(8) WDECL(9) WDECL(10) WDECL(11) WDECL(12)

    float c = 0.f, h = 0.f;

    for (int l = 0; l < 3; ++l) {
        // ---- weights: 4 rows (i,f,g,o of unit uc), K-half kh ----
        const float* Wsrc = kh ? Whh : Wih;
        const float* pI_ = Wsrc + ((size_t)l*100 + uc     ) * ND;
        const float* pF_ = Wsrc + ((size_t)l*100 + uc + 25) * ND;
        const float* pG_ = Wsrc + ((size_t)l*100 + uc + 50) * ND;
        const float* pO_ = Wsrc + ((size_t)l*100 + uc + 75) * ND;
        M12(WLOAD)
        wI12 = (f32x2){pI_[24], 0.f}; wF12 = (f32x2){pF_[24], 0.f};
        wG12 = (f32x2){pG_[24], 0.f}; wO12 = (f32x2){pO_[24], 0.f};
        const float bI = bih[l*100 + uc     ] + bhh[l*100 + uc     ];
        const float bF = bih[l*100 + uc + 25] + bhh[l*100 + uc + 25];
        const float bG = bih[l*100 + uc + 50] + bhh[l*100 + uc + 50];
        const float bO = bih[l*100 + uc + 75] + bhh[l*100 + uc + 75];

        // ---- per-layer init ----
        const float* src = ((l == 0) ? xin : ws) + (size_t)b * NT * ND + uc;
        float* const wsb = ws + (size_t)b * NT * ND + u;   // kh=1 store base
        c = 0.f; h = 0.f;
        float xa = 0.f, xb = 0.f;
        if (kh == 0 && au) {
            v[0][u] = src[0];          // x_0
            xa = src[ND];              // x_1
            xb = src[2*ND];            // x_2
        }
        if (kh == 1 && au) v[0][32 + u] = 0.f;   // h_{-1} = 0

        for (int t = 0; t < NT; ++t) {
            const int p = t & 1;
            const f32x4* const vv = (const f32x4*)&v[p][kh * 32];

            // ---- dot: 7 b128 reads + 52 pk_fma (own K-half only) ----
            f32x2 aI = {0.f,0.f}, aF = {0.f,0.f}, aG = {0.f,0.f}, aO = {0.f,0.f};
            {
                const f32x4 q0 = vv[0], q1 = vv[1];
                DOTP(0, LO2(q0)) DOTP(1, HI2(q0)) DOTP(2, LO2(q1)) DOTP(3, HI2(q1))
                const f32x4 q2 = vv[2], q3 = vv[3];
                DOTP(4, LO2(q2)) DOTP(5, HI2(q2)) DOTP(6, LO2(q3)) DOTP(7, HI2(q3))
                const f32x4 q4 = vv[4], q5 = vv[5], q6 = vv[6];
                DOTP(8, LO2(q4)) DOTP(9, HI2(q4)) DOTP(10, LO2(q5)) DOTP(11, HI2(q5))
                DOTP(12, LO2(q6))
            }

            // ---- cross-half combine (both halves end with full sums) ----
            float sI = aI.x + aI.y, sF = aF.x + aF.y;
            float sG = aG.x + aG.y, sO = aO.x + aO.y;
            sI += __shfl_xor(sI, 32);
            sF += __shfl_xor(sF, 32);
            sG += __shfl_xor(sG, 32);
            sO += __shfl_xor(sO, 32);

            // ---- gates + cell (redundant in both halves, lane-local) ----
            const float gi = sigf(sI + bI);
            const float gf = sigf(sF + bF);
            const float gg = tanhf_(sG + bG);
            const float go = sigf(sO + bO);
            c = fmaf(gf, c, gi * gg);
            h = go * tanhf_(c);

            // ---- publish (parity p^1): kh=1 -> h, kh=0 -> x_{t+1} ----
            if (au) {
                if (kh) {
                    v[p^1][32 + u] = h;
                    if (l < 2) wsb[(size_t)t * ND] = h;
                } else {
                    v[p^1][u] = xa;
                    xa = xb;
                    if (t + 3 < NT) xb = src[(size_t)(t + 3) * ND];
                }
            }
        }
        // drain ws stores before next layer's loads (same wave, same addrs)
        asm volatile("s_waitcnt vmcnt(0)" ::: "memory");
    }

    // ---- head: relu(h W1^T + b1) W2^T + b2, softmax(14) ----
    // final h_t was published to parity (511&1)^1 = 0 -> v[0][32+d]
    if (lane < 16) {
        float u1 = b1[lane];
#pragma unroll
        for (int d = 0; d < ND; ++d) u1 = fmaf(W1[lane*ND + d], v[0][32 + d], u1);
        v[0][lane] = fmaxf(u1, 0.f);     // overwrite x area (x consumed)
    }
    if (lane < 14) {
        float lg = b2[lane];
#pragma unroll
        for (int k = 0; k < 16; ++k) lg = fmaf(W2[lane*16 + k], v[0][k], lg);
        v[1][lane] = lg;
    }
    if (lane < 14) {
        float m = -1e30f;
#pragma unroll
        for (int j = 0; j < 14; ++j) m = fmaxf(m, v[1][j]);
        float s = 0.f;
#pragma unroll
        for (int j = 0; j < 14; ++j) s += exp2f_(1.442695041f * (v[1][j] - m));
        out[(size_t)b * 14 + lane] =
            exp2f_(1.442695041f * (v[1][lane] - m)) * rcpf_(s);
    }
}

extern "C" void kernel_launch(void* const* d_in, const int* in_sizes, int n_in,
                              void* d_out, int out_size, void* d_ws, size_t ws_size,
                              hipStream_t stream)
{
    const float* x   = (const float*)d_in[0];
    const float* Wih = (const float*)d_in[1];
    const float* Whh = (const float*)d_in[2];
    const float* bih = (const float*)d_in[3];
    const float* bhh = (const float*)d_in[4];
    const float* W1  = (const float*)d_in[5];
    const float* b1  = (const float*)d_in[6];
    const float* W2  = (const float*)d_in[7];
    const float* b2  = (const float*)d_in[8];
    float* outp = (float*)d_out;
    float* ws   = (float*)d_ws;   // 4096*512*25*4 = 209,715,200 bytes

    dim3 grid(4096), block(64);   // 4096 waves, one batch each
    hipLaunchKernelGGL(lstm12, grid, block, 0, stream,
                       x, Wih, Whh, bih, bhh, W1, b1, W2, b2, outp, ws);
}